// Round 8
// baseline (2091.685 us; speedup 1.0000x reference)
//
#include <hip/hip_runtime.h>

typedef unsigned short u16;
typedef __attribute__((ext_vector_type(8))) __bf16 bf16x8;
typedef __attribute__((ext_vector_type(4))) float floatx4;

#define B_ 2
#define L_ 512
#define D_ 1024
#define N_ 16
#define R_ 64
#define DEPTH_ 4
#define V_ 50000
#define MLP_ 4096
#define MROWS (B_ * L_)
#define SCAN_C 16
#define SCAN_S (L_ / SCAN_C)  // 32

// ---------- helpers ----------
__device__ __forceinline__ u16 f2b(float f) {  // hw RNE cvt
    return __builtin_bit_cast(u16, (__bf16)f);
}
__device__ __forceinline__ uint2 f4_to_b4(float4 v) {
    u16 a = f2b(v.x), b = f2b(v.y), c = f2b(v.z), d = f2b(v.w);
    uint2 r;
    r.x = (unsigned int)a | ((unsigned int)b << 16);
    r.y = (unsigned int)c | ((unsigned int)d << 16);
    return r;
}
__device__ __forceinline__ float silu_f(float v) { return v / (1.f + expf(-v)); }
__device__ __forceinline__ float gelu_f(float v) {
    return 0.5f * v * (1.f + erff(v * 0.7071067811865476f));
}
__device__ __forceinline__ float softplus_f(float v) {
    return fmaxf(v, 0.f) + log1pf(expf(-fabsf(v)));
}

// ---------- MFMA GEMM: C[M,N] = act(A[M,K] @ W[N,K](f32->bf16)^T + bias) ----------
// 1-D grid of mt*nt blocks; m = bid % mt (XCD-pinned A-tile), n = bid / mt.
template <int BM, int ACT, int RES, typename AT, typename OUT>
__global__ __launch_bounds__(256) void gemm_bt(
    const AT* __restrict__ A, const int lda,
    const float* __restrict__ W,
    const float* __restrict__ bias,
    OUT* __restrict__ out,
    const int N, const int K, const int mt) {
    constexpr int BN = 128, BK = 32;
    constexpr int WM = BM / 2;
    constexpr int MI = WM / 16;
    constexpr int WCH = (BN * BK / 4) / 256;  // 4 float4 chunks for W
    __shared__ alignas(16) u16 lA[BM * BK];
    __shared__ alignas(16) u16 lW[BN * BK];
    const int tid = threadIdx.x;
    const int lane = tid & 63, wv = tid >> 6;
    const int bid = blockIdx.x;
    const int m0 = (bid % mt) * BM, n0 = (bid / mt) * BN;
    const int wr = wv >> 1, wc = wv & 1;
    const int lr = lane & 15, kg = lane >> 4;

    floatx4 acc[MI][4];
#pragma unroll
    for (int i = 0; i < MI; ++i)
#pragma unroll
        for (int j = 0; j < 4; ++j) {
            floatx4 z4 = {0.f, 0.f, 0.f, 0.f};
            acc[i][j] = z4;
        }

    for (int kt = 0; kt < K; kt += BK) {
        if constexpr (sizeof(AT) == 2) {
            constexpr int ACH = (BM * BK * 2 / 16) / 256;  // 1 or 2 uint4 chunks
            uint4 ra[ACH];
            float4 rw[WCH];
#pragma unroll
            for (int i = 0; i < ACH; ++i) {
                const int idx = tid + i * 256;
                const int row = idx >> 2, colb = (idx & 3) * 16;
                ra[i] = *reinterpret_cast<const uint4*>(
                    (const char*)A + ((size_t)(m0 + row) * lda + kt) * 2 + colb);
            }
#pragma unroll
            for (int i = 0; i < WCH; ++i) {
                const int idx = tid + i * 256;
                const int row = idx >> 3, col4 = (idx & 7) * 4;
                int rn = n0 + row;
                rn = (rn < N) ? rn : (N - 1);
                rw[i] = *reinterpret_cast<const float4*>(&W[(size_t)rn * K + kt + col4]);
            }
            __syncthreads();
#pragma unroll
            for (int i = 0; i < ACH; ++i) reinterpret_cast<uint4*>(lA)[tid + i * 256] = ra[i];
#pragma unroll
            for (int i = 0; i < WCH; ++i) {
                const int idx = tid + i * 256;
                const int row = idx >> 3, col4 = (idx & 7) * 4;
                *reinterpret_cast<uint2*>(&lW[row * BK + col4]) = f4_to_b4(rw[i]);
            }
            __syncthreads();
        } else {
            constexpr int ACH = (BM * BK * 4 / 16) / 256;  // 2 or 4 float4 chunks
            float4 ra[ACH];
            float4 rw[WCH];
#pragma unroll
            for (int i = 0; i < ACH; ++i) {
                const int idx = tid + i * 256;
                const int row = idx >> 3, col4 = (idx & 7) * 4;
                ra[i] = *reinterpret_cast<const float4*>(&A[(size_t)(m0 + row) * lda + kt + col4]);
            }
#pragma unroll
            for (int i = 0; i < WCH; ++i) {
                const int idx = tid + i * 256;
                const int row = idx >> 3, col4 = (idx & 7) * 4;
                int rn = n0 + row;
                rn = (rn < N) ? rn : (N - 1);
                rw[i] = *reinterpret_cast<const float4*>(&W[(size_t)rn * K + kt + col4]);
            }
            __syncthreads();
#pragma unroll
            for (int i = 0; i < ACH; ++i) {
                const int idx = tid + i * 256;
                const int row = idx >> 3, col4 = (idx & 7) * 4;
                *reinterpret_cast<uint2*>(&lA[row * BK + col4]) = f4_to_b4(ra[i]);
            }
#pragma unroll
            for (int i = 0; i < WCH; ++i) {
                const int idx = tid + i * 256;
                const int row = idx >> 3, col4 = (idx & 7) * 4;
                *reinterpret_cast<uint2*>(&lW[row * BK + col4]) = f4_to_b4(rw[i]);
            }
            __syncthreads();
        }

        bf16x8 aF[MI], bF[4];
#pragma unroll
        for (int mi = 0; mi < MI; ++mi)
            aF[mi] = *reinterpret_cast<const bf16x8*>(&lA[(wr * WM + mi * 16 + lr) * BK + kg * 8]);
#pragma unroll
        for (int ni = 0; ni < 4; ++ni)
            bF[ni] = *reinterpret_cast<const bf16x8*>(&lW[(wc * 64 + ni * 16 + lr) * BK + kg * 8]);
#pragma unroll
        for (int mi = 0; mi < MI; ++mi)
#pragma unroll
            for (int ni = 0; ni < 4; ++ni)
                acc[mi][ni] = __builtin_amdgcn_mfma_f32_16x16x32_bf16(
                    aF[mi], bF[ni], acc[mi][ni], 0, 0, 0);
    }

    // epilogue: D layout col = lane&15, row = (lane>>4)*4 + r.
    // Loop order mi -> r -> ni so a row's 4x64B segments are written back-to-back
    // (L2 merges into full lines before eviction; avoids RMW write amplification).
#pragma unroll
    for (int mi = 0; mi < MI; ++mi) {
        const int rb = m0 + wr * WM + mi * 16 + kg * 4;
#pragma unroll
        for (int r = 0; r < 4; ++r) {
            const size_t rowoff = (size_t)(rb + r) * (size_t)N;
#pragma unroll
            for (int ni = 0; ni < 4; ++ni) {
                const int col = n0 + wc * 64 + ni * 16 + lr;
                if (col >= N) continue;
                float v = acc[mi][ni][r] + (bias ? bias[col] : 0.f);
                if constexpr (ACT == 1) v = gelu_f(v);
                if constexpr (ACT == 2) v = softplus_f(v);
                const size_t o = rowoff + (size_t)col;
                if constexpr (RES) {
                    out[o] += v;
                } else if constexpr (sizeof(OUT) == 2) {
                    out[o] = f2b(v);
                } else {
                    out[o] = v;
                }
            }
        }
    }
}

// ---------- timestep embedding base ----------
__global__ __launch_bounds__(256) void temb0_kernel(const int* __restrict__ ts,
                                                    float* __restrict__ temb0) {
    int i = blockIdx.x * 256 + threadIdx.x;
    if (i >= B_ * D_) return;
    int b = i >> 10, k = i & 1023;
    float t = (float)ts[b];
    int h = (k < 512) ? k : (k - 512);
    float f = expf((float)h * (-9.210340371976184f / 511.f));
    float e = t * f;
    temb0[i] = (k < 512) ? sinf(e) : cosf(e);
}

// ---------- small row-dot GEMM (M=B) ----------
template <int ACTV>
__global__ __launch_bounds__(256) void rowdot_kernel(const float* __restrict__ in,
                                                     const float* __restrict__ W,
                                                     const float* __restrict__ bias,
                                                     float* __restrict__ out,
                                                     const int Ncols, const int K) {
    const int g = (blockIdx.x * 256 + threadIdx.x) >> 6;
    const int lane = threadIdx.x & 63;
    if (g >= B_ * Ncols) return;
    const int b = g / Ncols, j = g % Ncols;
    const float* xr = in + (size_t)b * K;
    const float* wr = W + (size_t)j * K;
    float s = 0.f;
    for (int k = lane; k < K; k += 64) s += xr[k] * wr[k];
#pragma unroll
    for (int o = 32; o; o >>= 1) s += __shfl_xor(s, o);
    if (lane == 0) {
        float v = s + bias[j];
        if (ACTV == 1) v = silu_f(v);
        out[(size_t)b * Ncols + j] = v;
    }
}

// ---------- embedding + temb broadcast -> f32 residual stream ----------
__global__ __launch_bounds__(256) void embed_kernel(const int* __restrict__ ids,
                                                    const float* __restrict__ emb,
                                                    const float* __restrict__ temb2,
                                                    float* __restrict__ x) {
    const int gid = blockIdx.x * 256 + threadIdx.x;  // B*L*D/8
    const int d8 = gid & 127;
    const int row = gid >> 7;
    const int b = row >> 9;
    const int d0 = d8 * 8;
    const int id = ids[row];
    const float4 e0 = *reinterpret_cast<const float4*>(&emb[(size_t)id * D_ + d0]);
    const float4 e1 = *reinterpret_cast<const float4*>(&emb[(size_t)id * D_ + d0 + 4]);
    const float4 t0 = *reinterpret_cast<const float4*>(&temb2[b * D_ + d0]);
    const float4 t1 = *reinterpret_cast<const float4*>(&temb2[b * D_ + d0 + 4]);
    float4 o0, o1;
    o0.x = e0.x + t0.x; o0.y = e0.y + t0.y; o0.z = e0.z + t0.z; o0.w = e0.w + t0.w;
    o1.x = e1.x + t1.x; o1.y = e1.y + t1.y; o1.z = e1.z + t1.z; o1.w = e1.w + t1.w;
    *reinterpret_cast<float4*>(&x[(size_t)row * D_ + d0]) = o0;
    *reinterpret_cast<float4*>(&x[(size_t)row * D_ + d0 + 4]) = o1;
}

// ---------- LayerNorm (f32 in, bf16 out), one row per block ----------
__global__ __launch_bounds__(256) void ln_kernel(const float* __restrict__ x,
                                                 const float* __restrict__ s,
                                                 const float* __restrict__ bb,
                                                 u16* __restrict__ out) {
    __shared__ float red[4];
    const int row = blockIdx.x, tid = threadIdx.x;
    const float4 v = *reinterpret_cast<const float4*>(x + (size_t)row * D_ + tid * 4);
    float sm = v.x + v.y + v.z + v.w;
#pragma unroll
    for (int o = 1; o < 64; o <<= 1) sm += __shfl_xor(sm, o);
    if ((tid & 63) == 0) red[tid >> 6] = sm;
    __syncthreads();
    const float mean = (red[0] + red[1] + red[2] + red[3]) * (1.f / 1024.f);
    __syncthreads();
    const float dx = v.x - mean, dy = v.y - mean, dz = v.z - mean, dw = v.w - mean;
    float sq = dx * dx + dy * dy + dz * dz + dw * dw;
#pragma unroll
    for (int o = 1; o < 64; o <<= 1) sq += __shfl_xor(sq, o);
    if ((tid & 63) == 0) red[tid >> 6] = sq;
    __syncthreads();
    const float var = (red[0] + red[1] + red[2] + red[3]) * (1.f / 1024.f);
    const float rs = rsqrtf(var + 1e-5f);
    const int c = tid * 4;
    const float4 sv = *reinterpret_cast<const float4*>(&s[c]);
    const float4 bv = *reinterpret_cast<const float4*>(&bb[c]);
    float4 o;
    o.x = dx * rs * sv.x + bv.x;
    o.y = dy * rs * sv.y + bv.y;
    o.z = dz * rs * sv.z + bv.z;
    o.w = dw * rs * sv.w + bv.w;
    *reinterpret_cast<uint2*>(&out[(size_t)row * D_ + c]) = f4_to_b4(o);
}

// ---------- causal depthwise conv (K=4) + SiLU ----------
__global__ __launch_bounds__(256) void conv_silu_kernel(const float* __restrict__ xres,
                                                        const float* __restrict__ cw,
                                                        float* __restrict__ u) {
    const int gid = blockIdx.x * 256 + threadIdx.x;  // M*D/4
    const int d4 = gid & 255;
    const int row = gid >> 8;
    const int t = row & 511;
    const int b = row >> 9;
    const int d0 = d4 * 4;
    float wj[4][4];
#pragma unroll
    for (int j = 0; j < 4; ++j) {
        const float4 w4 = *reinterpret_cast<const float4*>(&cw[(d0 + j) * 4]);
        wj[j][0] = w4.x; wj[j][1] = w4.y; wj[j][2] = w4.z; wj[j][3] = w4.w;
    }
    float acc[4] = {};
#pragma unroll
    for (int k = 0; k < 4; ++k) {
        const int tt = t - 3 + k;
        if (tt < 0) continue;
        const float4 xv = *reinterpret_cast<const float4*>(&xres[(size_t)(b * L_ + tt) * D_ + d0]);
        acc[0] += xv.x * wj[0][k];
        acc[1] += xv.y * wj[1][k];
        acc[2] += xv.z * wj[2][k];
        acc[3] += xv.w * wj[3][k];
    }
    float4 o;
    o.x = silu_f(acc[0]); o.y = silu_f(acc[1]); o.z = silu_f(acc[2]); o.w = silu_f(acc[3]);
    *reinterpret_cast<float4*>(&u[(size_t)row * D_ + d0]) = o;
}

// ---------- chunked parallel selective scan ----------
__global__ __launch_bounds__(256) void scan_p1(const float* __restrict__ dt,
                                               const float* __restrict__ p,
                                               const float* __restrict__ u,
                                               const float* __restrict__ alog,
                                               float* __restrict__ Aprod,
                                               float* __restrict__ Hloc) {
    const int tid = threadIdx.x;
    const int ng = tid & 3;
    const int dl = tid >> 2;
    int blk = blockIdx.x;
    const int chunk = blk % SCAN_C; blk /= SCAN_C;
    const int dg = blk % (D_ / 64);
    const int b = blk / (D_ / 64);
    const int d = dg * 64 + dl;

    float a_v[4], inv_a[4];
#pragma unroll
    for (int j = 0; j < 4; ++j) {
        float av = -expf(alog[d * N_ + ng * 4 + j]);
        a_v[j] = av;
        inv_a[j] = 1.f / (av + 1e-10f);
    }

    __shared__ float pbuf[SCAN_S * 32];
    const int t0 = chunk * SCAN_S;
    {
        const int s = tid >> 3, off = (tid & 7) * 4;
        *reinterpret_cast<float4*>(&pbuf[s * 32 + off]) =
            *reinterpret_cast<const float4*>(&p[((size_t)(b * L_ + t0 + s)) * 96 + 64 + off]);
    }
    __syncthreads();

    float A[4] = {1.f, 1.f, 1.f, 1.f};
    float h[4] = {0.f, 0.f, 0.f, 0.f};
    for (int s = 0; s < SCAN_S; ++s) {
        const size_t idx = ((size_t)(b * L_ + t0 + s)) * D_ + d;
        const float dtv = dt[idx];
        const float uv = u[idx];
#pragma unroll
        for (int j = 0; j < 4; ++j) {
            const float ex = fminf(dtv * a_v[j], 0.f);
            const float at = expf(ex);
            const float bt = (fabsf(a_v[j]) < 1e-8f) ? dtv : (at - 1.f) * inv_a[j];
            const float bp = pbuf[s * 32 + ng * 4 + j];
            A[j] *= at;
            h[j] = at * h[j] + bt * bp * uv;
        }
    }
    const size_t o = ((size_t)(b * SCAN_C + chunk) * D_ + d) * N_ + ng * 4;
    float4 a4 = {A[0], A[1], A[2], A[3]};
    float4 h4 = {h[0], h[1], h[2], h[3]};
    *reinterpret_cast<float4*>(&Aprod[o]) = a4;
    *reinterpret_cast<float4*>(&Hloc[o]) = h4;
}

__global__ __launch_bounds__(256) void scan_p2(const float* __restrict__ Aprod,
                                               const float* __restrict__ Hloc,
                                               float* __restrict__ Hstart) {
    const int gid = blockIdx.x * 256 + threadIdx.x;  // B*D*N
    if (gid >= B_ * D_ * N_) return;
    const int b = gid / (D_ * N_);
    const int rem = gid % (D_ * N_);
    float H = 0.f;
    for (int k = 0; k < SCAN_C; ++k) {
        const size_t o = (size_t)(b * SCAN_C + k) * (D_ * N_) + rem;
        Hstart[o] = H;
        H = Aprod[o] * H + Hloc[o];
    }
}

__global__ __launch_bounds__(256) void scan_p3(const float* __restrict__ dt,
                                               const float* __restrict__ p,
                                               const float* __restrict__ u,
                                               const float* __restrict__ z,
                                               const float* __restrict__ alog,
                                               const float* __restrict__ Dp,
                                               const float* __restrict__ Hstart,
                                               u16* __restrict__ yg) {
    const int tid = threadIdx.x;
    const int ng = tid & 3;
    const int dl = tid >> 2;
    int blk = blockIdx.x;
    const int chunk = blk % SCAN_C; blk /= SCAN_C;
    const int dg = blk % (D_ / 64);
    const int b = blk / (D_ / 64);
    const int d = dg * 64 + dl;

    float a_v[4], inv_a[4];
#pragma unroll
    for (int j = 0; j < 4; ++j) {
        float av = -expf(alog[d * N_ + ng * 4 + j]);
        a_v[j] = av;
        inv_a[j] = 1.f / (av + 1e-10f);
    }
    const float Dpd = Dp[d];

    __shared__ float pbuf[SCAN_S * 32];
    const int t0 = chunk * SCAN_S;
    {
        const int s = tid >> 3, off = (tid & 7) * 4;
        *reinterpret_cast<float4*>(&pbuf[s * 32 + off]) =
            *reinterpret_cast<const float4*>(&p[((size_t)(b * L_ + t0 + s)) * 96 + 64 + off]);
    }
    __syncthreads();

    float h[4];
    {
        const size_t o = ((size_t)(b * SCAN_C + chunk) * D_ + d) * N_ + ng * 4;
        const float4 h4 = *reinterpret_cast<const float4*>(&Hstart[o]);
        h[0] = h4.x; h[1] = h4.y; h[2] = h4.z; h[3] = h4.w;
    }

    for (int s = 0; s < SCAN_S; ++s) {
        const size_t idx = ((size_t)(b * L_ + t0 + s)) * D_ + d;
        const float dtv = dt[idx];
        const float uv = u[idx];
        float yp = 0.f;
#pragma unroll
        for (int j = 0; j < 4; ++j) {
            const float ex = fminf(dtv * a_v[j], 0.f);
            const float at = expf(ex);
            const float bt = (fabsf(a_v[j]) < 1e-8f) ? dtv : (at - 1.f) * inv_a[j];
            const float bp = pbuf[s * 32 + ng * 4 + j];
            const float cp = pbuf[s * 32 + 16 + ng * 4 + j];
            h[j] = at * h[j] + bt * bp * uv;
            yp += cp * h[j];
        }
        yp += __shfl_xor(yp, 1);
        yp += __shfl_xor(yp, 2);
        if (ng == 0) {
            const float zv = z[idx];
            yg[idx] = f2b((yp + uv * Dpd) * silu_f(zv));
        }
    }
}

// ---------- launch ----------
extern "C" void kernel_launch(void* const* d_in, const int* in_sizes, int n_in,
                              void* d_out, int out_size, void* d_ws, size_t ws_size,
                              hipStream_t stream) {
    (void)in_sizes; (void)n_in; (void)out_size; (void)ws_size;
    const int* ids = (const int*)d_in[0];
    const int* tsteps = (const int*)d_in[1];
    const float* emb = (const float*)d_in[2];
    const float* tw1 = (const float*)d_in[3];
    const float* tb1 = (const float*)d_in[4];
    const float* tw2 = (const float*)d_in[5];
    const float* tb2 = (const float*)d_in[6];
    const float* ln1s = (const float*)d_in[7];
    const float* ln1b = (const float*)d_in[8];
    const float* wx = (const float*)d_in[9];
    const float* wz = (const float*)d_in[10];
    const float* wp = (const float*)d_in[11];
    const float* convw = (const float*)d_in[12];
    const float* dtw = (const float*)d_in[13];
    const float* dtb = (const float*)d_in[14];
    const float* alog = (const float*)d_in[15];
    const float* dp = (const float*)d_in[16];
    const float* wo = (const float*)d_in[17];
    const float* ln2s = (const float*)d_in[18];
    const float* ln2b = (const float*)d_in[19];
    const float* mw1 = (const float*)d_in[20];
    const float* mb1 = (const float*)d_in[21];
    const float* mw2 = (const float*)d_in[22];
    const float* mb2 = (const float*)d_in[23];
    const float* lnos = (const float*)d_in[24];
    const float* lnob = (const float*)d_in[25];
    const float* hw = (const float*)d_in[26];
    const float* hb = (const float*)d_in[27];
    float* outp = (float*)d_out;

    char* w = (char*)d_ws;
    auto alloc = [&](size_t bytes) {
        char* pp = w;
        w += (bytes + 255) & ~(size_t)255;
        return pp;
    };
    float* x = (float*)alloc((size_t)MROWS * D_ * 4);
    float* t0f = (float*)alloc((size_t)B_ * D_ * 4);
    float* t1f = (float*)alloc((size_t)B_ * MLP_ * 4);
    float* t2f = (float*)alloc((size_t)B_ * D_ * 4);
    u16* xnb = (u16*)alloc((size_t)MROWS * D_ * 2);
    float* xres = (float*)alloc((size_t)MROWS * D_ * 4);
    float* zf = (float*)alloc((size_t)MROWS * D_ * 4);
    float* pf = (float*)alloc((size_t)MROWS * 96 * 4);
    float* dtf = (float*)alloc((size_t)MROWS * D_ * 4);
    float* uf = (float*)alloc((size_t)MROWS * D_ * 4);
    u16* ygb = (u16*)alloc((size_t)MROWS * D_ * 2);
    // scratch in d_out's tail (fully overwritten by head GEMM at the end):
    u16* m1b = (u16*)outp;                            // 8.4 MB bf16 MLP hidden
    float* Aprod = outp + (size_t)6 * 1024 * 1024;    // 0.5M floats
    float* Hloc = outp + (size_t)7 * 1024 * 1024;     // 0.5M floats
    float* Hstart = outp + (size_t)8 * 1024 * 1024;   // 0.5M floats

    temb0_kernel<<<dim3((B_ * D_ + 255) / 256), dim3(256), 0, stream>>>(tsteps, t0f);
    rowdot_kernel<1><<<dim3(B_ * MLP_ / 4), dim3(256), 0, stream>>>(t0f, tw1, tb1, t1f, MLP_, D_);
    rowdot_kernel<0><<<dim3(B_ * D_ / 4), dim3(256), 0, stream>>>(t1f, tw2, tb2, t2f, D_, MLP_);
    embed_kernel<<<dim3(MROWS * D_ / 8 / 256), dim3(256), 0, stream>>>(ids, emb, t2f, x);

    for (int i = 0; i < DEPTH_; ++i) {
        const float* wxi = wx + (size_t)i * D_ * D_;
        const float* wzi = wz + (size_t)i * D_ * D_;
        const float* wpi = wp + (size_t)i * 96 * D_;
        const float* cwi = convw + (size_t)i * D_ * 4;
        const float* dtwi = dtw + (size_t)i * D_ * R_;
        const float* dtbi = dtb + (size_t)i * D_;
        const float* ali = alog + (size_t)i * D_ * N_;
        const float* dpi = dp + (size_t)i * D_;
        const float* woi = wo + (size_t)i * D_ * D_;
        const float* mw1i = mw1 + (size_t)i * MLP_ * D_;
        const float* mb1i = mb1 + (size_t)i * MLP_;
        const float* mw2i = mw2 + (size_t)i * D_ * MLP_;
        const float* mb2i = mb2 + (size_t)i * D_;

        ln_kernel<<<dim3(MROWS), dim3(256), 0, stream>>>(x, ln1s + i * D_, ln1b + i * D_, xnb);
        gemm_bt<64, 0, 0, u16, float><<<dim3(16 * 8), dim3(256), 0, stream>>>(
            xnb, D_, wxi, nullptr, xres, D_, D_, 16);
        gemm_bt<64, 0, 0, u16, float><<<dim3(16 * 8), dim3(256), 0, stream>>>(
            xnb, D_, wzi, nullptr, zf, D_, D_, 16);
        gemm_bt<64, 0, 0, u16, float><<<dim3(16 * 1), dim3(256), 0, stream>>>(
            xnb, D_, wpi, nullptr, pf, 96, D_, 16);
        gemm_bt<64, 2, 0, float, float><<<dim3(16 * 8), dim3(256), 0, stream>>>(
            pf, 96, dtwi, dtbi, dtf, D_, R_, 16);
        conv_silu_kernel<<<dim3(MROWS * D_ / 4 / 256), dim3(256), 0, stream>>>(xres, cwi, uf);
        scan_p1<<<dim3(B_ * (D_ / 64) * SCAN_C), dim3(256), 0, stream>>>(
            dtf, pf, uf, ali, Aprod, Hloc);
        scan_p2<<<dim3(B_ * D_ * N_ / 256), dim3(256), 0, stream>>>(Aprod, Hloc, Hstart);
        scan_p3<<<dim3(B_ * (D_ / 64) * SCAN_C), dim3(256), 0, stream>>>(
            dtf, pf, uf, zf, ali, dpi, Hstart, ygb);
        gemm_bt<64, 0, 1, u16, float><<<dim3(16 * 8), dim3(256), 0, stream>>>(
            ygb, D_, woi, nullptr, x, D_, D_, 16);
        ln_kernel<<<dim3(MROWS), dim3(256), 0, stream>>>(x, ln2s + i * D_, ln2b + i * D_, xnb);
        gemm_bt<128, 1, 0, u16, u16><<<dim3(8 * 32), dim3(256), 0, stream>>>(
            xnb, D_, mw1i, mb1i, m1b, MLP_, D_, 8);
        gemm_bt<64, 0, 1, u16, float><<<dim3(16 * 8), dim3(256), 0, stream>>>(
            m1b, MLP_, mw2i, mb2i, x, D_, MLP_, 16);
    }

    ln_kernel<<<dim3(MROWS), dim3(256), 0, stream>>>(x, lnos, lnob, xnb);
    gemm_bt<128, 0, 0, u16, float><<<dim3(8 * ((V_ + 127) / 128)), dim3(256), 0, stream>>>(
        xnb, D_, hw, hb, outp, V_, D_, 8);
}

// Round 9
// 1436.635 us; speedup vs baseline: 1.4560x; 1.4560x over previous
//
#include <hip/hip_runtime.h>

typedef unsigned short u16;
typedef __attribute__((ext_vector_type(8))) __bf16 bf16x8;
typedef __attribute__((ext_vector_type(4))) float floatx4;

#define B_ 2
#define L_ 512
#define D_ 1024
#define N_ 16
#define R_ 64
#define DEPTH_ 4
#define V_ 50000
#define MLP_ 4096
#define MROWS (B_ * L_)
#define SCAN_C 32
#define SCAN_S (L_ / SCAN_C)  // 16

// LDS XOR swizzle for 128-byte rows (BK=64 bf16): spreads the 16B column slots
// of 8 consecutive rows across all banks. Applied identically on store & read.
#define SWZ(b) ((b) ^ ((((b) >> 7) & 7) << 4))

// ---------- helpers ----------
__device__ __forceinline__ u16 f2b(float f) {  // hw RNE cvt
    return __builtin_bit_cast(u16, (__bf16)f);
}
__device__ __forceinline__ uint2 f4_to_b4(float4 v) {
    u16 a = f2b(v.x), b = f2b(v.y), c = f2b(v.z), d = f2b(v.w);
    uint2 r;
    r.x = (unsigned int)a | ((unsigned int)b << 16);
    r.y = (unsigned int)c | ((unsigned int)d << 16);
    return r;
}
__device__ __forceinline__ float silu_f(float v) { return v / (1.f + expf(-v)); }
__device__ __forceinline__ float gelu_f(float v) {
    return 0.5f * v * (1.f + erff(v * 0.7071067811865476f));
}
__device__ __forceinline__ float softplus_f(float v) {
    return fmaxf(v, 0.f) + log1pf(expf(-fabsf(v)));
}

// ---------- MFMA GEMM: C[M,N] = act(A[M,K] @ W[N,K](f32->bf16)^T + bias) ----------
// Pipelined: prologue load; per tile {barrier; regs->LDS; barrier; issue next loads; MFMA}.
// Optional fused second matrix (W2/out2): panels >= N/128 use W2/out2.
template <int BM, int ACT, int RES, typename AT, typename OUT>
__global__ __launch_bounds__(256) void gemm_bt(
    const AT* __restrict__ A, const int lda,
    const float* __restrict__ W, const float* __restrict__ W2,
    const float* __restrict__ bias,
    OUT* __restrict__ out, OUT* __restrict__ out2,
    const int N, const int K, const int mt) {
    constexpr int BN = 128, BK = 64;
    constexpr int WM = BM / 2;
    constexpr int MI = WM / 16;
    constexpr int WCH = BK / 8;            // float4 chunks per thread for W (8)
    constexpr int ACHU = (BM * BK) / 2048; // uint4 chunks per thread for bf16 A
    constexpr int ACHF = (BM * BK) / 1024; // float4 chunks per thread for f32 A
    __shared__ alignas(16) u16 lA[BM * BK];
    __shared__ alignas(16) u16 lW[BN * BK];
    const int tid = threadIdx.x;
    const int lane = tid & 63, wv = tid >> 6;
    const int bid = blockIdx.x;
    const int m0 = (bid % mt) * BM;
    int n0 = (bid / mt) * BN;
    const float* Wp = W;
    OUT* op = out;
    if (W2 != nullptr && n0 >= N) {
        Wp = W2;
        op = out2;
        n0 -= N;
    }
    const int wr = wv >> 1, wc = wv & 1;
    const int lr = lane & 15, kg = lane >> 4;

    uint4 raU[ACHU];
    float4 raF[ACHF];
    float4 rw[WCH];

    auto loadT = [&](int kt) {
        if constexpr (sizeof(AT) == 2) {
#pragma unroll
            for (int i = 0; i < ACHU; ++i) {
                const int idx = tid + i * 256;
                const int row = idx >> 3, cb = (idx & 7) * 16;
                raU[i] = *reinterpret_cast<const uint4*>(
                    (const char*)A + ((size_t)(m0 + row) * lda + kt) * 2 + cb);
            }
        } else {
#pragma unroll
            for (int i = 0; i < ACHF; ++i) {
                const int idx = tid + i * 256;
                const int row = idx >> 4, c4 = (idx & 15) * 4;
                raF[i] = *reinterpret_cast<const float4*>(&A[(size_t)(m0 + row) * lda + kt + c4]);
            }
        }
#pragma unroll
        for (int i = 0; i < WCH; ++i) {
            const int idx = tid + i * 256;
            const int row = idx >> 4, c4 = (idx & 15) * 4;
            int rn = n0 + row;
            rn = (rn < N) ? rn : (N - 1);
            rw[i] = *reinterpret_cast<const float4*>(&Wp[(size_t)rn * K + kt + c4]);
        }
    };
    auto storeT = [&]() {
        if constexpr (sizeof(AT) == 2) {
#pragma unroll
            for (int i = 0; i < ACHU; ++i) {
                const int idx = tid + i * 256;
                *reinterpret_cast<uint4*>((char*)lA + SWZ(idx * 16)) = raU[i];
            }
        } else {
#pragma unroll
            for (int i = 0; i < ACHF; ++i) {
                const int idx = tid + i * 256;
                const int row = idx >> 4, c4 = (idx & 15) * 4;
                *reinterpret_cast<uint2*>((char*)lA + SWZ(row * 128 + c4 * 2)) = f4_to_b4(raF[i]);
            }
        }
#pragma unroll
        for (int i = 0; i < WCH; ++i) {
            const int idx = tid + i * 256;
            const int row = idx >> 4, c4 = (idx & 15) * 4;
            *reinterpret_cast<uint2*>((char*)lW + SWZ(row * 128 + c4 * 2)) = f4_to_b4(rw[i]);
        }
    };

    floatx4 acc[MI][4];
#pragma unroll
    for (int i = 0; i < MI; ++i)
#pragma unroll
        for (int j = 0; j < 4; ++j) {
            floatx4 z4 = {0.f, 0.f, 0.f, 0.f};
            acc[i][j] = z4;
        }

    const int T = K / BK;
    loadT(0);
    for (int t = 0; t < T; ++t) {
        if (t) __syncthreads();
        storeT();
        __syncthreads();
        if (t + 1 < T) loadT((t + 1) * BK);
#pragma unroll
        for (int kk = 0; kk < 2; ++kk) {
            bf16x8 aF[MI], bF[4];
#pragma unroll
            for (int mi = 0; mi < MI; ++mi)
                aF[mi] = *reinterpret_cast<const bf16x8*>(
                    (const char*)lA + SWZ((wr * WM + mi * 16 + lr) * 128 + kk * 64 + kg * 16));
#pragma unroll
            for (int ni = 0; ni < 4; ++ni)
                bF[ni] = *reinterpret_cast<const bf16x8*>(
                    (const char*)lW + SWZ((wc * 64 + ni * 16 + lr) * 128 + kk * 64 + kg * 16));
#pragma unroll
            for (int mi = 0; mi < MI; ++mi)
#pragma unroll
                for (int ni = 0; ni < 4; ++ni)
                    acc[mi][ni] = __builtin_amdgcn_mfma_f32_16x16x32_bf16(
                        aF[mi], bF[ni], acc[mi][ni], 0, 0, 0);
        }
    }

    // epilogue: D layout col = lane&15, row = (lane>>4)*4 + r; mi->r->ni for merged lines.
#pragma unroll
    for (int mi = 0; mi < MI; ++mi) {
        const int rb = m0 + wr * WM + mi * 16 + kg * 4;
#pragma unroll
        for (int r = 0; r < 4; ++r) {
            const size_t rowoff = (size_t)(rb + r) * (size_t)N;
#pragma unroll
            for (int ni = 0; ni < 4; ++ni) {
                const int col = n0 + wc * 64 + ni * 16 + lr;
                if (col >= N) continue;
                float v = acc[mi][ni][r] + (bias ? bias[col] : 0.f);
                if constexpr (ACT == 1) v = gelu_f(v);
                if constexpr (ACT == 2) v = softplus_f(v);
                const size_t o = rowoff + (size_t)col;
                if constexpr (RES) {
                    op[o] += v;
                } else if constexpr (sizeof(OUT) == 2) {
                    op[o] = f2b(v);
                } else {
                    op[o] = v;
                }
            }
        }
    }
}

// ---------- timestep embedding base ----------
__global__ __launch_bounds__(256) void temb0_kernel(const int* __restrict__ ts,
                                                    float* __restrict__ temb0) {
    int i = blockIdx.x * 256 + threadIdx.x;
    if (i >= B_ * D_) return;
    int b = i >> 10, k = i & 1023;
    float t = (float)ts[b];
    int h = (k < 512) ? k : (k - 512);
    float f = expf((float)h * (-9.210340371976184f / 511.f));
    float e = t * f;
    temb0[i] = (k < 512) ? sinf(e) : cosf(e);
}

// ---------- small row-dot GEMM (M=B) ----------
template <int ACTV>
__global__ __launch_bounds__(256) void rowdot_kernel(const float* __restrict__ in,
                                                     const float* __restrict__ W,
                                                     const float* __restrict__ bias,
                                                     float* __restrict__ out,
                                                     const int Ncols, const int K) {
    const int g = (blockIdx.x * 256 + threadIdx.x) >> 6;
    const int lane = threadIdx.x & 63;
    if (g >= B_ * Ncols) return;
    const int b = g / Ncols, j = g % Ncols;
    const float* xr = in + (size_t)b * K;
    const float* wr = W + (size_t)j * K;
    float s = 0.f;
    for (int k = lane; k < K; k += 64) s += xr[k] * wr[k];
#pragma unroll
    for (int o = 32; o; o >>= 1) s += __shfl_xor(s, o);
    if (lane == 0) {
        float v = s + bias[j];
        if (ACTV == 1) v = silu_f(v);
        out[(size_t)b * Ncols + j] = v;
    }
}

// ---------- embedding + temb broadcast -> f32 residual stream ----------
__global__ __launch_bounds__(256) void embed_kernel(const int* __restrict__ ids,
                                                    const float* __restrict__ emb,
                                                    const float* __restrict__ temb2,
                                                    float* __restrict__ x) {
    const int gid = blockIdx.x * 256 + threadIdx.x;  // B*L*D/8
    const int d8 = gid & 127;
    const int row = gid >> 7;
    const int b = row >> 9;
    const int d0 = d8 * 8;
    const int id = ids[row];
    const float4 e0 = *reinterpret_cast<const float4*>(&emb[(size_t)id * D_ + d0]);
    const float4 e1 = *reinterpret_cast<const float4*>(&emb[(size_t)id * D_ + d0 + 4]);
    const float4 t0 = *reinterpret_cast<const float4*>(&temb2[b * D_ + d0]);
    const float4 t1 = *reinterpret_cast<const float4*>(&temb2[b * D_ + d0 + 4]);
    float4 o0, o1;
    o0.x = e0.x + t0.x; o0.y = e0.y + t0.y; o0.z = e0.z + t0.z; o0.w = e0.w + t0.w;
    o1.x = e1.x + t1.x; o1.y = e1.y + t1.y; o1.z = e1.z + t1.z; o1.w = e1.w + t1.w;
    *reinterpret_cast<float4*>(&x[(size_t)row * D_ + d0]) = o0;
    *reinterpret_cast<float4*>(&x[(size_t)row * D_ + d0 + 4]) = o1;
}

// ---------- LayerNorm (f32 in, bf16 out), one row per block ----------
__global__ __launch_bounds__(256) void ln_kernel(const float* __restrict__ x,
                                                 const float* __restrict__ s,
                                                 const float* __restrict__ bb,
                                                 u16* __restrict__ out) {
    __shared__ float red[4];
    const int row = blockIdx.x, tid = threadIdx.x;
    const float4 v = *reinterpret_cast<const float4*>(x + (size_t)row * D_ + tid * 4);
    float sm = v.x + v.y + v.z + v.w;
#pragma unroll
    for (int o = 1; o < 64; o <<= 1) sm += __shfl_xor(sm, o);
    if ((tid & 63) == 0) red[tid >> 6] = sm;
    __syncthreads();
    const float mean = (red[0] + red[1] + red[2] + red[3]) * (1.f / 1024.f);
    __syncthreads();
    const float dx = v.x - mean, dy = v.y - mean, dz = v.z - mean, dw = v.w - mean;
    float sq = dx * dx + dy * dy + dz * dz + dw * dw;
#pragma unroll
    for (int o = 1; o < 64; o <<= 1) sq += __shfl_xor(sq, o);
    if ((tid & 63) == 0) red[tid >> 6] = sq;
    __syncthreads();
    const float var = (red[0] + red[1] + red[2] + red[3]) * (1.f / 1024.f);
    const float rs = rsqrtf(var + 1e-5f);
    const int c = tid * 4;
    const float4 sv = *reinterpret_cast<const float4*>(&s[c]);
    const float4 bv = *reinterpret_cast<const float4*>(&bb[c]);
    float4 o;
    o.x = dx * rs * sv.x + bv.x;
    o.y = dy * rs * sv.y + bv.y;
    o.z = dz * rs * sv.z + bv.z;
    o.w = dw * rs * sv.w + bv.w;
    *reinterpret_cast<uint2*>(&out[(size_t)row * D_ + c]) = f4_to_b4(o);
}

// ---------- causal depthwise conv (K=4) + SiLU ----------
__global__ __launch_bounds__(256) void conv_silu_kernel(const float* __restrict__ xres,
                                                        const float* __restrict__ cw,
                                                        float* __restrict__ u) {
    const int gid = blockIdx.x * 256 + threadIdx.x;  // M*D/4
    const int d4 = gid & 255;
    const int row = gid >> 8;
    const int t = row & 511;
    const int b = row >> 9;
    const int d0 = d4 * 4;
    float wj[4][4];
#pragma unroll
    for (int j = 0; j < 4; ++j) {
        const float4 w4 = *reinterpret_cast<const float4*>(&cw[(d0 + j) * 4]);
        wj[j][0] = w4.x; wj[j][1] = w4.y; wj[j][2] = w4.z; wj[j][3] = w4.w;
    }
    float acc[4] = {};
#pragma unroll
    for (int k = 0; k < 4; ++k) {
        const int tt = t - 3 + k;
        if (tt < 0) continue;
        const float4 xv = *reinterpret_cast<const float4*>(&xres[(size_t)(b * L_ + tt) * D_ + d0]);
        acc[0] += xv.x * wj[0][k];
        acc[1] += xv.y * wj[1][k];
        acc[2] += xv.z * wj[2][k];
        acc[3] += xv.w * wj[3][k];
    }
    float4 o;
    o.x = silu_f(acc[0]); o.y = silu_f(acc[1]); o.z = silu_f(acc[2]); o.w = silu_f(acc[3]);
    *reinterpret_cast<float4*>(&u[(size_t)row * D_ + d0]) = o;
}

// ---------- chunked parallel selective scan ----------
__global__ __launch_bounds__(256) void scan_p1(const float* __restrict__ dt,
                                               const float* __restrict__ p,
                                               const float* __restrict__ u,
                                               const float* __restrict__ alog,
                                               float* __restrict__ Aprod,
                                               float* __restrict__ Hloc) {
    const int tid = threadIdx.x;
    const int ng = tid & 3;
    const int dl = tid >> 2;
    int blk = blockIdx.x;
    const int chunk = blk % SCAN_C; blk /= SCAN_C;
    const int dg = blk % (D_ / 64);
    const int b = blk / (D_ / 64);
    const int d = dg * 64 + dl;

    float a_v[4], inv_a[4];
#pragma unroll
    for (int j = 0; j < 4; ++j) {
        float av = -expf(alog[d * N_ + ng * 4 + j]);
        a_v[j] = av;
        inv_a[j] = 1.f / (av + 1e-10f);
    }

    __shared__ float pbuf[SCAN_S * 32];
    const int t0 = chunk * SCAN_S;
    if (tid < SCAN_S * 8) {
        const int s = tid >> 3, off = (tid & 7) * 4;
        *reinterpret_cast<float4*>(&pbuf[s * 32 + off]) =
            *reinterpret_cast<const float4*>(&p[((size_t)(b * L_ + t0 + s)) * 96 + 64 + off]);
    }
    __syncthreads();

    float A[4] = {1.f, 1.f, 1.f, 1.f};
    float h[4] = {0.f, 0.f, 0.f, 0.f};
#pragma unroll
    for (int s = 0; s < SCAN_S; ++s) {
        const size_t idx = ((size_t)(b * L_ + t0 + s)) * D_ + d;
        const float dtv = dt[idx];
        const float uv = u[idx];
#pragma unroll
        for (int j = 0; j < 4; ++j) {
            const float ex = fminf(dtv * a_v[j], 0.f);
            const float at = expf(ex);
            const float bt = (fabsf(a_v[j]) < 1e-8f) ? dtv : (at - 1.f) * inv_a[j];
            const float bp = pbuf[s * 32 + ng * 4 + j];
            A[j] *= at;
            h[j] = at * h[j] + bt * bp * uv;
        }
    }
    const size_t o = ((size_t)(b * SCAN_C + chunk) * D_ + d) * N_ + ng * 4;
    float4 a4 = {A[0], A[1], A[2], A[3]};
    float4 h4 = {h[0], h[1], h[2], h[3]};
    *reinterpret_cast<float4*>(&Aprod[o]) = a4;
    *reinterpret_cast<float4*>(&Hloc[o]) = h4;
}

__global__ __launch_bounds__(256) void scan_p2(const float* __restrict__ Aprod,
                                               const float* __restrict__ Hloc,
                                               float* __restrict__ Hstart) {
    const int gid = blockIdx.x * 256 + threadIdx.x;  // B*D*N
    if (gid >= B_ * D_ * N_) return;
    const int b = gid / (D_ * N_);
    const int rem = gid % (D_ * N_);
    float H = 0.f;
#pragma unroll 8
    for (int k = 0; k < SCAN_C; ++k) {
        const size_t o = (size_t)(b * SCAN_C + k) * (D_ * N_) + rem;
        Hstart[o] = H;
        H = Aprod[o] * H + Hloc[o];
    }
}

__global__ __launch_bounds__(256) void scan_p3(const float* __restrict__ dt,
                                               const float* __restrict__ p,
                                               const float* __restrict__ u,
                                               const float* __restrict__ z,
                                               const float* __restrict__ alog,
                                               const float* __restrict__ Dp,
                                               const float* __restrict__ Hstart,
                                               u16* __restrict__ yg) {
    const int tid = threadIdx.x;
    const int ng = tid & 3;
    const int dl = tid >> 2;
    int blk = blockIdx.x;
    const int chunk = blk % SCAN_C; blk /= SCAN_C;
    const int dg = blk % (D_ / 64);
    const int b = blk / (D_ / 64);
    const int d = dg * 64 + dl;

    float a_v[4], inv_a[4];
#pragma unroll
    for (int j = 0; j < 4; ++j) {
        float av = -expf(alog[d * N_ + ng * 4 + j]);
        a_v[j] = av;
        inv_a[j] = 1.f / (av + 1e-10f);
    }
    const float Dpd = Dp[d];

    __shared__ float pbuf[SCAN_S * 32];
    const int t0 = chunk * SCAN_S;
    if (tid < SCAN_S * 8) {
        const int s = tid >> 3, off = (tid & 7) * 4;
        *reinterpret_cast<float4*>(&pbuf[s * 32 + off]) =
            *reinterpret_cast<const float4*>(&p[((size_t)(b * L_ + t0 + s)) * 96 + 64 + off]);
    }
    __syncthreads();

    float h[4];
    {
        const size_t o = ((size_t)(b * SCAN_C + chunk) * D_ + d) * N_ + ng * 4;
        const float4 h4 = *reinterpret_cast<const float4*>(&Hstart[o]);
        h[0] = h4.x; h[1] = h4.y; h[2] = h4.z; h[3] = h4.w;
    }

#pragma unroll
    for (int s = 0; s < SCAN_S; ++s) {
        const size_t idx = ((size_t)(b * L_ + t0 + s)) * D_ + d;
        const float dtv = dt[idx];
        const float uv = u[idx];
        float yp = 0.f;
#pragma unroll
        for (int j = 0; j < 4; ++j) {
            const float ex = fminf(dtv * a_v[j], 0.f);
            const float at = expf(ex);
            const float bt = (fabsf(a_v[j]) < 1e-8f) ? dtv : (at - 1.f) * inv_a[j];
            const float bp = pbuf[s * 32 + ng * 4 + j];
            const float cp = pbuf[s * 32 + 16 + ng * 4 + j];
            h[j] = at * h[j] + bt * bp * uv;
            yp += cp * h[j];
        }
        yp += __shfl_xor(yp, 1);
        yp += __shfl_xor(yp, 2);
        if (ng == 0) {
            const float zv = z[idx];
            yg[idx] = f2b((yp + uv * Dpd) * silu_f(zv));
        }
    }
}

// ---------- launch ----------
extern "C" void kernel_launch(void* const* d_in, const int* in_sizes, int n_in,
                              void* d_out, int out_size, void* d_ws, size_t ws_size,
                              hipStream_t stream) {
    (void)in_sizes; (void)n_in; (void)out_size; (void)ws_size;
    const int* ids = (const int*)d_in[0];
    const int* tsteps = (const int*)d_in[1];
    const float* emb = (const float*)d_in[2];
    const float* tw1 = (const float*)d_in[3];
    const float* tb1 = (const float*)d_in[4];
    const float* tw2 = (const float*)d_in[5];
    const float* tb2 = (const float*)d_in[6];
    const float* ln1s = (const float*)d_in[7];
    const float* ln1b = (const float*)d_in[8];
    const float* wx = (const float*)d_in[9];
    const float* wz = (const float*)d_in[10];
    const float* wp = (const float*)d_in[11];
    const float* convw = (const float*)d_in[12];
    const float* dtw = (const float*)d_in[13];
    const float* dtb = (const float*)d_in[14];
    const float* alog = (const float*)d_in[15];
    const float* dp = (const float*)d_in[16];
    const float* wo = (const float*)d_in[17];
    const float* ln2s = (const float*)d_in[18];
    const float* ln2b = (const float*)d_in[19];
    const float* mw1 = (const float*)d_in[20];
    const float* mb1 = (const float*)d_in[21];
    const float* mw2 = (const float*)d_in[22];
    const float* mb2 = (const float*)d_in[23];
    const float* lnos = (const float*)d_in[24];
    const float* lnob = (const float*)d_in[25];
    const float* hw = (const float*)d_in[26];
    const float* hb = (const float*)d_in[27];
    float* outp = (float*)d_out;

    char* w = (char*)d_ws;
    auto alloc = [&](size_t bytes) {
        char* pp = w;
        w += (bytes + 255) & ~(size_t)255;
        return pp;
    };
    float* x = (float*)alloc((size_t)MROWS * D_ * 4);
    float* t0f = (float*)alloc((size_t)B_ * D_ * 4);
    float* t1f = (float*)alloc((size_t)B_ * MLP_ * 4);
    float* t2f = (float*)alloc((size_t)B_ * D_ * 4);
    u16* xnb = (u16*)alloc((size_t)MROWS * D_ * 2);
    float* xres = (float*)alloc((size_t)MROWS * D_ * 4);
    float* zf = (float*)alloc((size_t)MROWS * D_ * 4);
    float* pf = (float*)alloc((size_t)MROWS * 96 * 4);
    float* dtf = (float*)alloc((size_t)MROWS * D_ * 4);
    float* uf = (float*)alloc((size_t)MROWS * D_ * 4);
    u16* ygb = (u16*)alloc((size_t)MROWS * D_ * 2);
    // scratch in d_out's tail (fully overwritten by head GEMM at the end):
    u16* m1b = (u16*)outp;                            // bf16 MLP hidden (4.2M floats worth)
    float* Aprod = outp + (size_t)6 * 1024 * 1024;    // 1M floats
    float* Hloc = outp + (size_t)8 * 1024 * 1024;     // 1M floats
    float* Hstart = outp + (size_t)10 * 1024 * 1024;  // 1M floats

    temb0_kernel<<<dim3((B_ * D_ + 255) / 256), dim3(256), 0, stream>>>(tsteps, t0f);
    rowdot_kernel<1><<<dim3(B_ * MLP_ / 4), dim3(256), 0, stream>>>(t0f, tw1, tb1, t1f, MLP_, D_);
    rowdot_kernel<0><<<dim3(B_ * D_ / 4), dim3(256), 0, stream>>>(t1f, tw2, tb2, t2f, D_, MLP_);
    embed_kernel<<<dim3(MROWS * D_ / 8 / 256), dim3(256), 0, stream>>>(ids, emb, t2f, x);

    for (int i = 0; i < DEPTH_; ++i) {
        const float* wxi = wx + (size_t)i * D_ * D_;
        const float* wzi = wz + (size_t)i * D_ * D_;
        const float* wpi = wp + (size_t)i * 96 * D_;
        const float* cwi = convw + (size_t)i * D_ * 4;
        const float* dtwi = dtw + (size_t)i * D_ * R_;
        const float* dtbi = dtb + (size_t)i * D_;
        const float* ali = alog + (size_t)i * D_ * N_;
        const float* dpi = dp + (size_t)i * D_;
        const float* woi = wo + (size_t)i * D_ * D_;
        const float* mw1i = mw1 + (size_t)i * MLP_ * D_;
        const float* mb1i = mb1 + (size_t)i * MLP_;
        const float* mw2i = mw2 + (size_t)i * D_ * MLP_;
        const float* mb2i = mb2 + (size_t)i * D_;

        ln_kernel<<<dim3(MROWS), dim3(256), 0, stream>>>(x, ln1s + i * D_, ln1b + i * D_, xnb);
        // fused wx+wz (shared A): 32 m-tiles x 16 panels = 512 blocks
        gemm_bt<32, 0, 0, u16, float><<<dim3(512), dim3(256), 0, stream>>>(
            xnb, D_, wxi, wzi, nullptr, xres, zf, D_, D_, 32);
        gemm_bt<32, 0, 0, u16, float><<<dim3(32), dim3(256), 0, stream>>>(
            xnb, D_, wpi, nullptr, nullptr, pf, nullptr, 96, D_, 32);
        gemm_bt<32, 2, 0, float, float><<<dim3(256), dim3(256), 0, stream>>>(
            pf, 96, dtwi, nullptr, dtbi, dtf, nullptr, D_, R_, 32);
        conv_silu_kernel<<<dim3(MROWS * D_ / 4 / 256), dim3(256), 0, stream>>>(xres, cwi, uf);
        scan_p1<<<dim3(B_ * (D_ / 64) * SCAN_C), dim3(256), 0, stream>>>(
            dtf, pf, uf, ali, Aprod, Hloc);
        scan_p2<<<dim3(B_ * D_ * N_ / 256), dim3(256), 0, stream>>>(Aprod, Hloc, Hstart);
        scan_p3<<<dim3(B_ * (D_ / 64) * SCAN_C), dim3(256), 0, stream>>>(
            dtf, pf, uf, zf, ali, dpi, Hstart, ygb);
        gemm_bt<32, 0, 1, u16, float><<<dim3(256), dim3(256), 0, stream>>>(
            ygb, D_, woi, nullptr, nullptr, x, nullptr, D_, D_, 32);
        ln_kernel<<<dim3(MROWS), dim3(256), 0, stream>>>(x, ln2s + i * D_, ln2b + i * D_, xnb);
        gemm_bt<64, 1, 0, u16, u16><<<dim3(512), dim3(256), 0, stream>>>(
            xnb, D_, mw1i, nullptr, mb1i, m1b, nullptr, MLP_, D_, 16);
        gemm_bt<32, 0, 1, u16, float><<<dim3(256), dim3(256), 0, stream>>>(
            m1b, MLP_, mw2i, nullptr, mb2i, x, nullptr, D_, MLP_, 32);
    }

    ln_kernel<<<dim3(MROWS), dim3(256), 0, stream>>>(x, lnos, lnob, xnb);
    gemm_bt<128, 0, 0, u16, float><<<dim3(8 * ((V_ + 127) / 128)), dim3(256), 0, stream>>>(
        xnb, D_, hw, nullptr, hb, outp, nullptr, V_, D_, 8);
}